// Round 2
// baseline (820.038 us; speedup 1.0000x reference)
//
#include <hip/hip_runtime.h>
#include <stdint.h>

// ---------------------------------------------------------------------------
// StyledMLP fp32 I/O: 3x (modulated 1x1 conv + bias + leaky_relu*sqrt2).
// Internal compute: bf16 MFMA (16x16x32), fp32 accumulate.
// Layer0 fuses the (b,c,n)->(n,c) transpose; h0 staged bf16 in d_out;
// h1 staged bf16 in d_ws. Final layer writes fp32 native (b,co,n).
// ---------------------------------------------------------------------------

#define B_   16
#define C_   256        // Cin = Chid = Cout
#define N_   16384
#define S_   512
#define CP   264        // padded channel dim for bf16 intermediates (528B rows)
#define NT   64         // spatial tile per GEMM block
#define SLAB_BYTES 20480            // 256 rows * 80B (32k bf16 + 8 pad)
#define SLAB_ELEMS 10240
#define XT_BYTES (NT * CP * 2)      // 33792
#define WOFF XT_BYTES
#define LAYER_SLAB_ELEMS (B_ * 8 * SLAB_ELEMS)

typedef __attribute__((ext_vector_type(8))) short bf16x8;
typedef __attribute__((ext_vector_type(4))) float f32x4;

__device__ __forceinline__ float bf2f(uint32_t h) {
  union { uint32_t u; float f; } v; v.u = h << 16; return v.f;
}
__device__ __forceinline__ uint16_t f2bf(float f) {
  union { float f; uint32_t u; } v; v.f = f;
  return (uint16_t)((v.u + 0x7FFFu + ((v.u >> 16) & 1u)) >> 16);
}
__device__ __forceinline__ void gl_lds16(const void* g, void* l) {
  __builtin_amdgcn_global_load_lds(
      (const __attribute__((address_space(1))) void*)g,
      (__attribute__((address_space(3))) void*)l, 16, 0, 0);
}
__device__ __forceinline__ uint16_t actbf(float v) {
  v = (v >= 0.f) ? v : 0.2f * v;
  return f2bf(v * 1.4142135623730951f);
}
__device__ __forceinline__ float actf(float v) {
  v = (v >= 0.f) ? v : 0.2f * v;
  return v * 1.4142135623730951f;
}

// ---------------------------------------------------------------------------
// Weight kernel: one block per sample b (one launch per layer). fp32 inputs.
// style = (z @ mw^T)/sqrt(S) + mb ; wb = w*style/sqrt(Cin) ; demod ; -> bf16
// Output: per (b, kstep): 256 rows x (32 bf16 + 8 pad) = 20480B slab.
// ---------------------------------------------------------------------------
__global__ __launch_bounds__(256) void wkern(
    const float* __restrict__ z, const float* __restrict__ w,
    const float* __restrict__ mw, const float* __restrict__ mb,
    uint16_t* __restrict__ slab_l) {
  __shared__ float zsh[S_];
  __shared__ float stylesh[C_];
  const int b = blockIdx.x;
  const int t = threadIdx.x;

  zsh[t]       = z[b * S_ + t];
  zsh[t + 256] = z[b * S_ + t + 256];
  __syncthreads();

  {  // style for input channel t
    const float* row = mw + (size_t)t * S_;
    float dot = 0.f;
    for (int j = 0; j < S_; j += 4) {
      float4 a = *(const float4*)(row + j);
      dot = fmaf(a.x, zsh[j + 0], dot);
      dot = fmaf(a.y, zsh[j + 1], dot);
      dot = fmaf(a.z, zsh[j + 2], dot);
      dot = fmaf(a.w, zsh[j + 3], dot);
    }
    stylesh[t] = dot * 0.04419417382415922f /*1/sqrt(512)*/ + mb[t];
  }
  __syncthreads();

  // output row t: modulate, demodulate, pack bf16 into K-blocked slabs
  const float* wrow = w + (size_t)t * C_;
  float ssum = 0.f;
  for (int i = 0; i < C_; i += 4) {
    float4 a = *(const float4*)(wrow + i);
    float t0 = 0.0625f * a.x * stylesh[i + 0];
    float t1 = 0.0625f * a.y * stylesh[i + 1];
    float t2 = 0.0625f * a.z * stylesh[i + 2];
    float t3 = 0.0625f * a.w * stylesh[i + 3];
    ssum = fmaf(t0, t0, fmaf(t1, t1, fmaf(t2, t2, fmaf(t3, t3, ssum))));
  }
  const float demod = rsqrtf(ssum + 1e-8f);
  for (int i = 0; i < C_; i += 8) {
    uint16_t hv[8];
#pragma unroll
    for (int k = 0; k < 8; ++k)
      hv[k] = f2bf(0.0625f * wrow[i + k] * stylesh[i + k] * demod);
    uint4 o;
    o.x = (uint32_t)hv[0] | ((uint32_t)hv[1] << 16);
    o.y = (uint32_t)hv[2] | ((uint32_t)hv[3] << 16);
    o.z = (uint32_t)hv[4] | ((uint32_t)hv[5] << 16);
    o.w = (uint32_t)hv[6] | ((uint32_t)hv[7] << 16);
    const int ks = i >> 5, off = i & 31;
    *(uint4*)(slab_l + (size_t)(b * 8 + ks) * SLAB_ELEMS + t * 40 + off) = o;
  }
}

// ---------------------------------------------------------------------------
// GEMM layer 0: x in native fp32 (b, 256c, 16384n). Fused transpose+cast:
// per K-step stage 32c x 64n into LDS as bf16 (n-major, 40-halfword rows).
// Output: bf16 (b, n, CP) into d_out's low region (h0).
// LDS map: BX tile [0, 5120) ; W slab [5120, 25600) ; epilogue reuses [0, XT).
// ---------------------------------------------------------------------------
__global__ __launch_bounds__(256, 3) void gemm0(
    const float* __restrict__ xg, const uint16_t* __restrict__ slabs_l,
    const float* __restrict__ bias, uint16_t* __restrict__ out) {
  __shared__ __align__(16) unsigned char lds[XT_BYTES];
  const int bx = blockIdx.x;
  const int b = bx >> 8, tl = bx & 255;
  const int n0 = tl * NT;
  const int t = threadIdx.x;
  const int wv = t >> 6, lane = t & 63;
  const int ln = lane & 15, q = lane >> 4;

  f32x4 acc[4][4];
#pragma unroll
  for (int mi = 0; mi < 4; ++mi)
#pragma unroll
    for (int ni = 0; ni < 4; ++ni) acc[mi][ni] = (f32x4){0.f, 0.f, 0.f, 0.f};

  const char* wbase = (const char*)slabs_l + (size_t)b * (8 * SLAB_BYTES);
  const float* xb = xg + (size_t)b * C_ * N_ + n0;

  for (int ks = 0; ks < 8; ++ks) {
    // W slab: 20 x 1KB wave-issues
    const char* wsrc = wbase + ks * SLAB_BYTES;
    for (int i = wv; i < 20; i += 4)
      gl_lds16(wsrc + i * 1024 + lane * 16, lds + 5120 + i * 1024);
    // X block: c = ks*32 + wv*8 + i, n = n0 + lane (coalesced 256B/wave)
    uint16_t hv[8];
#pragma unroll
    for (int i = 0; i < 8; ++i)
      hv[i] = f2bf(xb[(size_t)(ks * 32 + wv * 8 + i) * N_ + lane]);
    uint4 o;
    o.x = (uint32_t)hv[0] | ((uint32_t)hv[1] << 16);
    o.y = (uint32_t)hv[2] | ((uint32_t)hv[3] << 16);
    o.z = (uint32_t)hv[4] | ((uint32_t)hv[5] << 16);
    o.w = (uint32_t)hv[6] | ((uint32_t)hv[7] << 16);
    *(uint4*)(lds + lane * 80 + wv * 16) = o;
    __syncthreads();

    bf16x8 af[4], bfr[4];
#pragma unroll
    for (int mi = 0; mi < 4; ++mi)
      af[mi] = *(const bf16x8*)(lds + 5120 + (wv * 64 + mi * 16 + ln) * 80 + q * 16);
#pragma unroll
    for (int ni = 0; ni < 4; ++ni)
      bfr[ni] = *(const bf16x8*)(lds + (ni * 16 + ln) * 80 + q * 16);
#pragma unroll
    for (int mi = 0; mi < 4; ++mi)
#pragma unroll
      for (int ni = 0; ni < 4; ++ni)
        acc[mi][ni] = __builtin_amdgcn_mfma_f32_16x16x32_bf16(
            af[mi], bfr[ni], acc[mi][ni], 0, 0, 0);
    __syncthreads();
  }

  // epilogue: bias + act -> bf16 (n, CP) tile in LDS -> contiguous store
  uint16_t* ltile = (uint16_t*)lds;
#pragma unroll
  for (int mi = 0; mi < 4; ++mi) {
    const int cb = wv * 64 + mi * 16 + q * 4;
    float4 b4 = *(const float4*)(bias + cb);
#pragma unroll
    for (int ni = 0; ni < 4; ++ni) {
      const int n = ni * 16 + ln;
      uint16_t h0 = actbf(acc[mi][ni][0] + b4.x);
      uint16_t h1 = actbf(acc[mi][ni][1] + b4.y);
      uint16_t h2 = actbf(acc[mi][ni][2] + b4.z);
      uint16_t h3 = actbf(acc[mi][ni][3] + b4.w);
      uint2 pk;
      pk.x = (uint32_t)h0 | ((uint32_t)h1 << 16);
      pk.y = (uint32_t)h2 | ((uint32_t)h3 << 16);
      *(uint2*)(&ltile[n * CP + cb]) = pk;
    }
  }
  __syncthreads();
  char* dst = (char*)(out + ((size_t)b * N_ + n0) * CP);
  for (int i = 0; i < 9; ++i) {
    const int off = i * 4096 + t * 16;
    if (off < XT_BYTES)
      *(uint4*)(dst + off) = *(const uint4*)((const char*)lds + off);
  }
}

// ---------------------------------------------------------------------------
// GEMM layers 1/2: input bf16 (b, n, CP). FINAL writes fp32 native (b,co,n);
// else bf16 (b, n, CP).
// ---------------------------------------------------------------------------
template <bool FINAL>
__global__ __launch_bounds__(256, 2) void gemm12(
    const uint16_t* __restrict__ xg,       // (b, n, CP) bf16
    const uint16_t* __restrict__ slabs_l,  // layer slab base
    const float* __restrict__ bias,        // fp32 (C_)
    void* __restrict__ outp) {
  __shared__ __align__(16) unsigned char lds[XT_BYTES + SLAB_BYTES];
  const int bx = blockIdx.x;
  const int b = bx >> 8, tl = bx & 255;
  const int n0 = tl * NT;
  const int t = threadIdx.x;
  const int wv = t >> 6, lane = t & 63;
  const int ln = lane & 15, q = lane >> 4;

  // X tile: 33 x 1KB wave-issues, contiguous (all K)
  const char* xsrc = (const char*)(xg + ((size_t)b * N_ + n0) * CP);
  for (int i = wv; i < 33; i += 4)
    gl_lds16(xsrc + i * 1024 + lane * 16, lds + i * 1024);

  f32x4 acc[4][4];
#pragma unroll
  for (int mi = 0; mi < 4; ++mi)
#pragma unroll
    for (int ni = 0; ni < 4; ++ni) acc[mi][ni] = (f32x4){0.f, 0.f, 0.f, 0.f};

  const char* wbase = (const char*)slabs_l + (size_t)b * (8 * SLAB_BYTES);
  for (int ks = 0; ks < 8; ++ks) {
    const char* wsrc = wbase + ks * SLAB_BYTES;
    for (int i = wv; i < 20; i += 4)
      gl_lds16(wsrc + i * 1024 + lane * 16, lds + WOFF + i * 1024);
    __syncthreads();

    bf16x8 af[4], bfr[4];
#pragma unroll
    for (int mi = 0; mi < 4; ++mi)
      af[mi] = *(const bf16x8*)(lds + WOFF + (wv * 64 + mi * 16 + ln) * 80 + q * 16);
#pragma unroll
    for (int ni = 0; ni < 4; ++ni)
      bfr[ni] = *(const bf16x8*)((const uint16_t*)lds + (ni * 16 + ln) * CP + ks * 32 + q * 8);
#pragma unroll
    for (int mi = 0; mi < 4; ++mi)
#pragma unroll
      for (int ni = 0; ni < 4; ++ni)
        acc[mi][ni] = __builtin_amdgcn_mfma_f32_16x16x32_bf16(
            af[mi], bfr[ni], acc[mi][ni], 0, 0, 0);
    __syncthreads();
  }

  if (!FINAL) {
    uint16_t* out = (uint16_t*)outp;
    uint16_t* ltile = (uint16_t*)lds;
#pragma unroll
    for (int mi = 0; mi < 4; ++mi) {
      const int cb = wv * 64 + mi * 16 + q * 4;
      float4 b4 = *(const float4*)(bias + cb);
#pragma unroll
      for (int ni = 0; ni < 4; ++ni) {
        const int n = ni * 16 + ln;
        uint16_t h0 = actbf(acc[mi][ni][0] + b4.x);
        uint16_t h1 = actbf(acc[mi][ni][1] + b4.y);
        uint16_t h2 = actbf(acc[mi][ni][2] + b4.z);
        uint16_t h3 = actbf(acc[mi][ni][3] + b4.w);
        uint2 pk;
        pk.x = (uint32_t)h0 | ((uint32_t)h1 << 16);
        pk.y = (uint32_t)h2 | ((uint32_t)h3 << 16);
        *(uint2*)(&ltile[n * CP + cb]) = pk;
      }
    }
    __syncthreads();
    char* dst = (char*)(out + ((size_t)b * N_ + n0) * CP);
    for (int i = 0; i < 9; ++i) {
      const int off = i * 4096 + t * 16;
      if (off < XT_BYTES)
        *(uint4*)(dst + off) = *(const uint4*)((const char*)lds + off);
    }
  } else {
    float* out = (float*)outp;
    float* obase = out + (size_t)b * C_ * N_ + n0;
#pragma unroll
    for (int mi = 0; mi < 4; ++mi) {
      const int cb = wv * 64 + mi * 16 + q * 4;
      float4 b4 = *(const float4*)(bias + cb);
      float bb[4] = {b4.x, b4.y, b4.z, b4.w};
#pragma unroll
      for (int ni = 0; ni < 4; ++ni) {
        const int n = ni * 16 + ln;
#pragma unroll
        for (int r = 0; r < 4; ++r)
          obase[(size_t)(cb + r) * N_ + n] = actf(acc[mi][ni][r] + bb[r]);
      }
    }
  }
}

// ---------------------------------------------------------------------------
extern "C" void kernel_launch(void* const* d_in, const int* in_sizes, int n_in,
                              void* d_out, int out_size, void* d_ws,
                              size_t ws_size, hipStream_t stream) {
  (void)in_sizes; (void)n_in; (void)out_size; (void)ws_size;
  const float* x = (const float*)d_in[0];
  const float* z = (const float*)d_in[1];
  const float* w_[3]  = {(const float*)d_in[2], (const float*)d_in[6],  (const float*)d_in[10]};
  const float* mw_[3] = {(const float*)d_in[3], (const float*)d_in[7],  (const float*)d_in[11]};
  const float* mb_[3] = {(const float*)d_in[4], (const float*)d_in[8],  (const float*)d_in[12]};
  const float* bb_[3] = {(const float*)d_in[5], (const float*)d_in[9],  (const float*)d_in[13]};

  char* ws = (char*)d_ws;
  uint16_t* wslabs = (uint16_t*)ws;                 // 7.86 MB (3 layers)
  uint16_t* h1     = (uint16_t*)(ws + 8388608);     // 138.4 MB bf16 (b,n,CP)
  uint16_t* h0     = (uint16_t*)d_out;              // low 138.4 MB of d_out

  for (int l = 0; l < 3; ++l)
    wkern<<<B_, 256, 0, stream>>>(z, w_[l], mw_[l], mb_[l],
                                  wslabs + (size_t)l * LAYER_SLAB_ELEMS);

  gemm0<<<B_ * 256, 256, 0, stream>>>(x, wslabs, bb_[0], h0);
  gemm12<false><<<B_ * 256, 256, 0, stream>>>(h0, wslabs + LAYER_SLAB_ELEMS,
                                              bb_[1], h1);
  gemm12<true><<<B_ * 256, 256, 0, stream>>>(h1, wslabs + 2 * (size_t)LAYER_SLAB_ELEMS,
                                             bb_[2], d_out);
}